// Round 6
// baseline (298.672 us; speedup 1.0000x reference)
//
#include <hip/hip_runtime.h>

// AttentionAggregator bf16-MFMA pipeline, R6. B=16, N=1024, D=512, H=8, HD=64.
// 4 launches: castW ; gemm_qkv (A = fp32 loaded DIRECT to regs + in-reg cvt,
// W via gload_lds counted-vmcnt dbuf, XCD swizzle, V->Vt transposed) ;
// attn (2-phase dbuf, in-reg P, lsum-via-MFMA-ones, setprio) ; gemm_wo.

#define B_  16
#define N_  1024
#define D_  512
#define M_  (B_ * N_)   // 16384

typedef short short8 __attribute__((ext_vector_type(8)));
typedef float f32x4 __attribute__((ext_vector_type(4)));
typedef unsigned short ushort;
typedef unsigned int uint;

__device__ __forceinline__ ushort bf16rne(float f) {
  uint u = __float_as_uint(f);
  u += 0x7FFFu + ((u >> 16) & 1u);
  return (ushort)(u >> 16);
}
__device__ __forceinline__ uint bf16pk(float lo, float hi) {
  return (uint)bf16rne(lo) | ((uint)bf16rne(hi) << 16);
}
__device__ __forceinline__ void gload_lds16(const void* g, void* l) {
  __builtin_amdgcn_global_load_lds(
      (const __attribute__((address_space(1))) uint*)g,
      (__attribute__((address_space(3))) uint*)l, 16, 0, 0);
}
__device__ __forceinline__ float exp2_hw(float x) {
  float r;
  asm("v_exp_f32 %0, %1" : "=v"(r) : "v"(x));
  return r;
}
__device__ __forceinline__ uint cvtpk_bf16(float lo, float hi) {
  uint r;
  asm("v_cvt_pk_bf16_f32 %0, %1, %2" : "=v"(r) : "v"(lo), "v"(hi));
  return r;
}

union U4S8 { uint u[4]; short8 s; };

// ---- weight cast ----------------------------------------------------------
__global__ __launch_bounds__(256) void castW_k(
    const float* __restrict__ w0, const float* __restrict__ w1,
    const float* __restrict__ w2, const float* __restrict__ w3,
    ushort* __restrict__ d, long n)
{
  const int z = blockIdx.y;
  const float* s = (z == 0) ? w0 : (z == 1) ? w1 : (z == 2) ? w2 : w3;
  const float sc = (z == 0) ? 0.1803368801f : 1.f;   // (1/8)*log2(e) into Wq
  ushort* dz = d + (long)z * n;
  long i = ((long)blockIdx.x * 256 + threadIdx.x) * 8;
  float4 v0 = *(const float4*)(s + i);
  float4 v1 = *(const float4*)(s + i + 4);
  uint4 o;
  o.x = bf16pk(v0.x * sc, v0.y * sc); o.y = bf16pk(v0.z * sc, v0.w * sc);
  o.z = bf16pk(v1.x * sc, v1.y * sc); o.w = bf16pk(v1.z * sc, v1.w * sc);
  *(uint4*)(dz + i) = o;
}

// ---- GEMM 128x128, BK=64, XCD swizzle.
// MODE 0: A = fp32 (x_q/x/r by z) loaded DIRECT to registers, cvt in-reg;
//         W bf16 via gload_lds 2-deep counted-vmcnt dbuf; V -> Vt transposed.
// MODE 1: A = bf16 (heads), both via gload_lds dbuf, fp32 out. --------------
template <int MODE>
__global__ __launch_bounds__(256) void gemm_k(
    const float* __restrict__ Af0, const float* __restrict__ Af1,
    const float* __restrict__ Af2, const ushort* __restrict__ Abf,
    const ushort* __restrict__ Wbase, void* __restrict__ C0,
    ushort* __restrict__ Vt)
{
  const long SB = (long)M_ * D_, WB = (long)D_ * D_;
  const int nwg = gridDim.x, per = nwg >> 3;
  const int wg = ((int)blockIdx.x & 7) * per + ((int)blockIdx.x >> 3);
  int z, bx, by;
  if constexpr (MODE == 0) { z = wg >> 9; bx = wg & 3; by = (wg & 511) >> 2; }
  else                     { z = 0;       bx = wg & 3; by = wg >> 2; }
  const ushort* W = (MODE == 0) ? Wbase + z * WB : Wbase;

  __shared__ __align__(16) ushort Bl[2][128 * 64];
  const int t = threadIdx.x, lane = t & 63, w = t >> 6;
  const int g = lane >> 4, lr = lane & 15;
  const int wr = w >> 1, wc = w & 1;
  const long m0 = (long)by * 128, n0 = (long)bx * 128;

  f32x4 acc[4][4] = {};

  auto LOADW = [&](int k0, int bufi) {
    #pragma unroll
    for (int u = 0; u < 4; ++u) {
      const int a = t * 16 + u * 4096;
      const int row = a >> 7, ch = (a >> 4) & 7;
      const int kk = k0 + ((ch ^ (row & 7)) << 3);
      gload_lds16(W + (n0 + row) * D_ + kk, (char*)Bl[bufi] + a);
    }
  };

  auto READB = [&](int cur, short8 (&bf)[4][2]) {
    #pragma unroll
    for (int nf = 0; nf < 4; ++nf)
      #pragma unroll
      for (int ks = 0; ks < 2; ++ks) {
        const int row = wc * 64 + nf * 16 + lr;
        bf[nf][ks] = *(const short8*)((const char*)Bl[cur] + row * 128 + (((ks * 4 + g) ^ (row & 7)) << 4));
      }
  };

  if constexpr (MODE == 0) {
    const float* A = (z == 0) ? Af0 : (z == 1) ? Af1 : Af2;
    const float* Aw = A + (m0 + wr * 64 + lr) * D_;   // wave-private rows

    float4 rA[16];
    auto LOADA = [&](int k0) {
      #pragma unroll
      for (int mf = 0; mf < 4; ++mf)
        #pragma unroll
        for (int ks = 0; ks < 2; ++ks) {
          const float* p = Aw + (long)mf * 16 * D_ + k0 + ks * 32 + g * 8;
          rA[mf * 4 + ks * 2 + 0] = *(const float4*)p;
          rA[mf * 4 + ks * 2 + 1] = *(const float4*)(p + 4);
        }
    };
    auto CVTA = [&](short8 (&af)[4][2]) {
      #pragma unroll
      for (int mf = 0; mf < 4; ++mf)
        #pragma unroll
        for (int ks = 0; ks < 2; ++ks) {
          const float4 a0 = rA[mf * 4 + ks * 2 + 0];
          const float4 a1 = rA[mf * 4 + ks * 2 + 1];
          U4S8 u;
          u.u[0] = cvtpk_bf16(a0.x, a0.y); u.u[1] = cvtpk_bf16(a0.z, a0.w);
          u.u[2] = cvtpk_bf16(a1.x, a1.y); u.u[3] = cvtpk_bf16(a1.z, a1.w);
          af[mf][ks] = u.s;
        }
    };

    LOADA(0);          // 16 vmem
    LOADW(0, 0);       // +4 = 20
    LOADW(64, 1);      // +4 = 24

    #pragma unroll
    for (int it = 0; it < 8; ++it) {
      const int cur = it & 1;
      // drain A(it)+W(it); keep W(it+1) (4 loads) in flight
      if (it < 7) asm volatile("s_waitcnt vmcnt(4)" ::: "memory");
      else        asm volatile("s_waitcnt vmcnt(0)" ::: "memory");
      __builtin_amdgcn_s_barrier();

      short8 af[4][2], bf[4][2];
      CVTA(af);
      if (it + 1 < 8) LOADA((it + 1) * 64);   // reuse rA; full iter of flight
      READB(cur, bf);

      #pragma unroll
      for (int mf = 0; mf < 4; ++mf)
        #pragma unroll
        for (int nf = 0; nf < 4; ++nf)
          #pragma unroll
          for (int ks = 0; ks < 2; ++ks)
            acc[mf][nf] = __builtin_amdgcn_mfma_f32_16x16x32_bf16(
                af[mf][ks], bf[nf][ks], acc[mf][nf], 0, 0, 0);

      asm volatile("s_waitcnt lgkmcnt(0)" ::: "memory");
      __builtin_amdgcn_s_barrier();
      if (it + 2 < 8) LOADW((it + 2) * 64, cur);
    }
  } else {
    const ushort* A = Abf;
    __shared__ __align__(16) ushort Al[2][128 * 64];
    auto STAGE = [&](int k0, int bufi) {
      #pragma unroll
      for (int u = 0; u < 4; ++u) {
        const int a = t * 16 + u * 4096;
        const int row = a >> 7, ch = (a >> 4) & 7;
        const int kk = k0 + ((ch ^ (row & 7)) << 3);
        gload_lds16(A + (m0 + row) * D_ + kk, (char*)Al[bufi] + a);
        gload_lds16(W + (n0 + row) * D_ + kk, (char*)Bl[bufi] + a);
      }
    };
    STAGE(0, 0);
    STAGE(64, 1);
    #pragma unroll
    for (int it = 0; it < 8; ++it) {
      const int cur = it & 1;
      if (it < 7) asm volatile("s_waitcnt vmcnt(8)" ::: "memory");
      else        asm volatile("s_waitcnt vmcnt(0)" ::: "memory");
      __builtin_amdgcn_s_barrier();
      short8 af[4][2], bf[4][2];
      #pragma unroll
      for (int mf = 0; mf < 4; ++mf)
        #pragma unroll
        for (int ks = 0; ks < 2; ++ks) {
          const int row = wr * 64 + mf * 16 + lr;
          af[mf][ks] = *(const short8*)((const char*)Al[cur] + row * 128 + (((ks * 4 + g) ^ (row & 7)) << 4));
        }
      READB(cur, bf);
      #pragma unroll
      for (int mf = 0; mf < 4; ++mf)
        #pragma unroll
        for (int nf = 0; nf < 4; ++nf)
          #pragma unroll
          for (int ks = 0; ks < 2; ++ks)
            acc[mf][nf] = __builtin_amdgcn_mfma_f32_16x16x32_bf16(
                af[mf][ks], bf[nf][ks], acc[mf][nf], 0, 0, 0);
      asm volatile("s_waitcnt lgkmcnt(0)" ::: "memory");
      __builtin_amdgcn_s_barrier();
      if (it < 6) STAGE((it + 2) * 64, cur);
    }
  }

  if constexpr (MODE == 1) {
    float* C = (float*)C0;
    #pragma unroll
    for (int mf = 0; mf < 4; ++mf)
      #pragma unroll
      for (int nf = 0; nf < 4; ++nf)
        #pragma unroll
        for (int r = 0; r < 4; ++r)
          C[(m0 + wr * 64 + mf * 16 + g * 4 + r) * D_ + n0 + wc * 64 + nf * 16 + lr] =
              acc[mf][nf][r];
  } else {
    if (z < 2) {
      ushort* C = (ushort*)C0 + z * SB;
      #pragma unroll
      for (int mf = 0; mf < 4; ++mf)
        #pragma unroll
        for (int nf = 0; nf < 4; ++nf)
          #pragma unroll
          for (int r = 0; r < 4; ++r)
            C[(m0 + wr * 64 + mf * 16 + g * 4 + r) * D_ + n0 + wc * 64 + nf * 16 + lr] =
                bf16rne(acc[mf][nf][r]);
    } else {
      // V: write transposed per head -> Vt[(b*8+h)*64 + c][kv]
      const int hh = (int)(n0 >> 6) + wc;
      #pragma unroll
      for (int mf = 0; mf < 4; ++mf) {
        const long m = m0 + wr * 64 + mf * 16 + g * 4;
        const int bb = (int)(m >> 10);
        const int kv = (int)(m & 1023);
        #pragma unroll
        for (int nf = 0; nf < 4; ++nf) {
          const int c = nf * 16 + lr;
          uint2 o2;
          o2.x = cvtpk_bf16(acc[mf][nf][0], acc[mf][nf][1]);
          o2.y = cvtpk_bf16(acc[mf][nf][2], acc[mf][nf][3]);
          *(uint2*)&Vt[((long)(bb * 8 + hh) * 64 + c) * (long)N_ + kv] = o2;
        }
      }
    }
  }
}

// ---- attention: 4 waves x 32 q-rows, KV tile 64, 2-phase dbuf staging,
// swapped QK^T, 2^s, in-reg P via permlane swaps, lsum via MFMA-ones. --------
__global__ __launch_bounds__(256) void attn_mfma(
    const ushort* __restrict__ Q, const ushort* __restrict__ K,
    const ushort* __restrict__ Vt, ushort* __restrict__ Hd)
{
  __shared__ __align__(16) ushort Kl[2][64 * 64];
  __shared__ __align__(16) ushort Vl[2][64 * 64];
  const int t = threadIdx.x, lane = t & 63, w = t >> 6;
  const int g = lane >> 4, lr = lane & 15;
  const int bid = blockIdx.x;
  const int z = bid & 127, b = z >> 3, h = z & 7;   // same z -> same XCD
  const int qbase = (bid >> 7) * 128 + w * 32;

  short8 qf[2][2];
  #pragma unroll
  for (int nf = 0; nf < 2; ++nf)
    #pragma unroll
    for (int ks = 0; ks < 2; ++ks)
      qf[nf][ks] = *(const short8*)(Q + (long)(b * N_ + qbase + nf * 16 + lr) * D_ + h * 64 + ks * 32 + g * 8);

  const short8 ones = {0x3F80, 0x3F80, 0x3F80, 0x3F80, 0x3F80, 0x3F80, 0x3F80, 0x3F80};

  f32x4 o[2][4] = {};
  f32x4 acc_l[2] = {};

  const ushort* Kz = K + (long)b * N_ * D_ + h * 64;
  const ushort* Vz = Vt + (long)z * 64 * N_;

  auto STAGE = [&](int kt, int bufi) {
    #pragma unroll
    for (int u = 0; u < 2; ++u) {
      const int a = t * 16 + u * 4096;
      const int row = a >> 7, ch = (a >> 4) & 7;
      const int cc = (ch ^ (row & 7)) << 3;
      gload_lds16(Kz + (long)(kt * 64 + row) * D_ + cc, (char*)Kl[bufi] + a);
      gload_lds16(Vz + (long)row * N_ + kt * 64 + cc, (char*)Vl[bufi] + a);
    }
  };

  STAGE(0, 0);
  __syncthreads();

  for (int kt = 0; kt < 16; ++kt) {
    const int cur = kt & 1;
    if (kt < 15) STAGE(kt + 1, cur ^ 1);

    // S^T[kv][q] = K_tile @ Q^T  (lane: q=lr, kv=16mf+4g+r)
    f32x4 s[4][2] = {};
    __builtin_amdgcn_s_setprio(1);
    #pragma unroll
    for (int mf = 0; mf < 4; ++mf) {
      short8 kf[2];
      #pragma unroll
      for (int ks = 0; ks < 2; ++ks) {
        const int row = mf * 16 + lr;
        kf[ks] = *(const short8*)((const char*)Kl[cur] + row * 128 + (((ks * 4 + g) ^ (row & 7)) << 4));
      }
      #pragma unroll
      for (int nf = 0; nf < 2; ++nf)
        #pragma unroll
        for (int ks = 0; ks < 2; ++ks)
          s[mf][nf] = __builtin_amdgcn_mfma_f32_16x16x32_bf16(kf[ks], qf[nf][ks], s[mf][nf], 0, 0, 0);
    }
    __builtin_amdgcn_s_setprio(0);

    // P = 2^S, pack to bf16, redistribute to PV A-frag layout in-register
    short8 pa[2][2];
    #pragma unroll
    for (int nf = 0; nf < 2; ++nf) {
      uint Apk[4], Bpk[4];
      #pragma unroll
      for (int mf = 0; mf < 4; ++mf) {
        const float e0 = exp2_hw(s[mf][nf][0]);
        const float e1 = exp2_hw(s[mf][nf][1]);
        const float e2 = exp2_hw(s[mf][nf][2]);
        const float e3 = exp2_hw(s[mf][nf][3]);
        Apk[mf] = cvtpk_bf16(e0, e1);
        Bpk[mf] = cvtpk_bf16(e2, e3);
      }
      asm("v_permlane32_swap_b32 %0, %1" : "+v"(Apk[0]), "+v"(Apk[1]));
      asm("v_permlane16_swap_b32 %0, %1" : "+v"(Apk[0]), "+v"(Apk[1]));
      asm("v_permlane32_swap_b32 %0, %1" : "+v"(Bpk[0]), "+v"(Bpk[1]));
      asm("v_permlane16_swap_b32 %0, %1" : "+v"(Bpk[0]), "+v"(Bpk[1]));
      asm("v_permlane32_swap_b32 %0, %1" : "+v"(Apk[2]), "+v"(Apk[3]));
      asm("v_permlane16_swap_b32 %0, %1" : "+v"(Apk[2]), "+v"(Apk[3]));
      asm("v_permlane32_swap_b32 %0, %1" : "+v"(Bpk[2]), "+v"(Bpk[3]));
      asm("v_permlane16_swap_b32 %0, %1" : "+v"(Bpk[2]), "+v"(Bpk[3]));
      U4S8 u0, u1;
      u0.u[0] = Apk[0]; u0.u[1] = Bpk[0]; u0.u[2] = Apk[1]; u0.u[3] = Bpk[1];
      u1.u[0] = Apk[2]; u1.u[1] = Bpk[2]; u1.u[2] = Apk[3]; u1.u[3] = Bpk[3];
      pa[nf][0] = u0.s;
      pa[nf][1] = u1.s;
    }

    // out += P @ V ; row-sums via ones-B MFMA (lands in epilogue layout)
    __builtin_amdgcn_s_setprio(1);
    #pragma unroll
    for (int ks = 0; ks < 2; ++ks) {
      short8 vb[4];
      #pragma unroll
      for (int nf = 0; nf < 4; ++nf) {
        const int row = nf * 16 + lr;
        vb[nf] = *(const short8*)((const char*)Vl[cur] + row * 128 + (((ks * 4 + g) ^ (row & 7)) << 4));
      }
      #pragma unroll
      for (int mf = 0; mf < 2; ++mf) {
        #pragma unroll
        for (int nf = 0; nf < 4; ++nf)
          o[mf][nf] = __builtin_amdgcn_mfma_f32_16x16x32_bf16(pa[mf][ks], vb[nf], o[mf][nf], 0, 0, 0);
        acc_l[mf] = __builtin_amdgcn_mfma_f32_16x16x32_bf16(pa[mf][ks], ones, acc_l[mf], 0, 0, 0);
      }
    }
    __builtin_amdgcn_s_setprio(0);
    __syncthreads();
  }

  // acc_l[mf][r] = row-sum for q = mf*16 + g*4 + r (same for every lr col)
  #pragma unroll
  for (int mf = 0; mf < 2; ++mf)
    #pragma unroll
    for (int r = 0; r < 4; ++r) {
      const float inv = 1.f / acc_l[mf][r];
      const long grow = (long)b * N_ + qbase + mf * 16 + g * 4 + r;
      #pragma unroll
      for (int nf = 0; nf < 4; ++nf)
        Hd[grow * D_ + h * 64 + nf * 16 + lr] = bf16rne(o[mf][nf][r] * inv);
    }
}

extern "C" void kernel_launch(void* const* d_in, const int* in_sizes, int n_in,
                              void* d_out, int out_size, void* d_ws, size_t ws_size,
                              hipStream_t stream) {
  const float* x   = (const float*)d_in[0];
  const float* r   = (const float*)d_in[1];
  const float* x_q = (const float*)d_in[2];
  const float* Wq  = (const float*)d_in[3];
  const float* Wk  = (const float*)d_in[4];
  const float* Wv  = (const float*)d_in[5];
  const float* Wo  = (const float*)d_in[6];

  const long SBe = (long)M_ * D_;      // 8,388,608
  const long WBe = (long)D_ * D_;      // 262,144
  ushort* Qb  = (ushort*)d_ws;
  ushort* Kb  = Qb  + SBe;
  ushort* Vtb = Kb  + SBe;
  ushort* Hdb = Vtb + SBe;
  ushort* Wqb = Hdb + SBe;             // weights contiguous: Wq,Wk,Wv,Wo

  dim3 blk(256);
  castW_k<<<dim3(128, 4), blk, 0, stream>>>(Wq, Wk, Wv, Wo, Wqb, WBe);

  gemm_k<0><<<dim3(1536), blk, 0, stream>>>(x_q, x, r, nullptr, Wqb, Qb, Vtb);

  attn_mfma<<<dim3(1024), blk, 0, stream>>>(Qb, Kb, Vtb, Hdb);

  gemm_k<1><<<dim3(512), blk, 0, stream>>>(nullptr, nullptr, nullptr, Hdb,
                                           Wqb + 3 * WBe, d_out, nullptr);
}

// Round 7
// 245.956 us; speedup vs baseline: 1.2143x; 1.2143x over previous
//
#include <hip/hip_runtime.h>

// AttentionAggregator bf16-MFMA pipeline, R7. B=16, N=1024, D=512, H=8, HD=64.
// 4 launches: castW ; gemm_qkv (A staged as RAW FP32 via global_load_lds,
// BK=32, cvt-to-bf16 at fragment read; W bf16 dbuf; counted-vmcnt 2-deep;
// XCD swizzle; V->Vt transposed) ; attn (2-phase dbuf, in-reg P via permlane,
// lsum-via-MFMA-ones, setprio) ; gemm_wo (bf16 A, fp32 out).

#define B_  16
#define N_  1024
#define D_  512
#define M_  (B_ * N_)   // 16384

typedef short short8 __attribute__((ext_vector_type(8)));
typedef float f32x4 __attribute__((ext_vector_type(4)));
typedef unsigned short ushort;
typedef unsigned int uint;

__device__ __forceinline__ ushort bf16rne(float f) {
  uint u = __float_as_uint(f);
  u += 0x7FFFu + ((u >> 16) & 1u);
  return (ushort)(u >> 16);
}
__device__ __forceinline__ uint bf16pk(float lo, float hi) {
  return (uint)bf16rne(lo) | ((uint)bf16rne(hi) << 16);
}
__device__ __forceinline__ void gload_lds16(const void* g, void* l) {
  __builtin_amdgcn_global_load_lds(
      (const __attribute__((address_space(1))) uint*)g,
      (__attribute__((address_space(3))) uint*)l, 16, 0, 0);
}
__device__ __forceinline__ float exp2_hw(float x) {
  float r;
  asm("v_exp_f32 %0, %1" : "=v"(r) : "v"(x));
  return r;
}
__device__ __forceinline__ uint cvtpk_bf16(float lo, float hi) {
  uint r;
  asm("v_cvt_pk_bf16_f32 %0, %1, %2" : "=v"(r) : "v"(lo), "v"(hi));
  return r;
}

union U4S8 { uint u[4]; short8 s; };

// ---- weight cast ----------------------------------------------------------
__global__ __launch_bounds__(256) void castW_k(
    const float* __restrict__ w0, const float* __restrict__ w1,
    const float* __restrict__ w2, const float* __restrict__ w3,
    ushort* __restrict__ d, long n)
{
  const int z = blockIdx.y;
  const float* s = (z == 0) ? w0 : (z == 1) ? w1 : (z == 2) ? w2 : w3;
  const float sc = (z == 0) ? 0.1803368801f : 1.f;   // (1/8)*log2(e) into Wq
  ushort* dz = d + (long)z * n;
  long i = ((long)blockIdx.x * 256 + threadIdx.x) * 8;
  float4 v0 = *(const float4*)(s + i);
  float4 v1 = *(const float4*)(s + i + 4);
  uint4 o;
  o.x = bf16pk(v0.x * sc, v0.y * sc); o.y = bf16pk(v0.z * sc, v0.w * sc);
  o.z = bf16pk(v1.x * sc, v1.y * sc); o.w = bf16pk(v1.z * sc, v1.w * sc);
  *(uint4*)(dz + i) = o;
}

// ---- GEMM 128x128, XCD swizzle.
// MODE 0: A = fp32 staged RAW via gload_lds (BK=32), cvt at fragment read;
//         W bf16 dbuf; 2-deep counted vmcnt; V -> Vt transposed.
// MODE 1: A,W bf16 via gload_lds dbuf (BK=64), fp32 out. --------------------
template <int MODE>
__global__ __launch_bounds__(256) void gemm_k(
    const float* __restrict__ Af0, const float* __restrict__ Af1,
    const float* __restrict__ Af2, const ushort* __restrict__ Abf,
    const ushort* __restrict__ Wbase, void* __restrict__ C0,
    ushort* __restrict__ Vt)
{
  const long SB = (long)M_ * D_, WB = (long)D_ * D_;
  const int nwg = gridDim.x, per = nwg >> 3;
  const int wg = ((int)blockIdx.x & 7) * per + ((int)blockIdx.x >> 3);
  int z, bx, by;
  if constexpr (MODE == 0) { z = wg >> 9; bx = wg & 3; by = (wg & 511) >> 2; }
  else                     { z = 0;       bx = wg & 3; by = wg >> 2; }

  const int t = threadIdx.x, lane = t & 63, w = t >> 6;
  const int g = lane >> 4, lr = lane & 15;
  const int wr = w >> 1, wc = w & 1;
  const long m0 = (long)by * 128, n0 = (long)bx * 128;

  f32x4 acc[4][4] = {};

  if constexpr (MODE == 0) {
    const float* A = (z == 0) ? Af0 : (z == 1) ? Af1 : Af2;
    const ushort* W = Wbase + z * WB;
    __shared__ __align__(16) float  Afl[2][128 * 32];   // 2 x 16 KB
    __shared__ __align__(16) ushort Wl[2][128 * 32];    // 2 x 8 KB

    auto STAGE = [&](int k0, int bufi) {
      #pragma unroll
      for (int u = 0; u < 4; ++u) {           // A: 16 KB, 128B rows
        const int a = t * 16 + u * 4096;
        const int row = a >> 7, ch = (a >> 4) & 7;
        gload_lds16(A + (m0 + row) * D_ + k0 + ((ch ^ (row & 7)) << 2),
                    (char*)Afl[bufi] + a);
      }
      #pragma unroll
      for (int u = 0; u < 2; ++u) {           // W: 8 KB, 64B rows
        const int a = t * 16 + u * 4096;
        const int row = a >> 6, ch = (a >> 4) & 3;
        const int sw = (row & 3) ^ ((row >> 2) & 3);
        gload_lds16(W + (n0 + row) * D_ + k0 + ((ch ^ sw) << 3),
                    (char*)Wl[bufi] + a);
      }
    };

    STAGE(0, 0);     // 6 vmem/thread
    STAGE(32, 1);    // 12 in flight

    #pragma unroll
    for (int it = 0; it < 16; ++it) {
      const int cur = it & 1;
      if (it < 15) asm volatile("s_waitcnt vmcnt(6)" ::: "memory");
      else         asm volatile("s_waitcnt vmcnt(0)" ::: "memory");
      __builtin_amdgcn_s_barrier();

      short8 af[4], bf[4];
      #pragma unroll
      for (int mf = 0; mf < 4; ++mf) {
        const int row = wr * 64 + mf * 16 + lr;
        const int c0 = (2 * g) ^ (row & 7), c1 = (2 * g + 1) ^ (row & 7);
        f32x4 lo = *(const f32x4*)((const char*)Afl[cur] + row * 128 + (c0 << 4));
        f32x4 hi = *(const f32x4*)((const char*)Afl[cur] + row * 128 + (c1 << 4));
        U4S8 u;
        u.u[0] = cvtpk_bf16(lo[0], lo[1]); u.u[1] = cvtpk_bf16(lo[2], lo[3]);
        u.u[2] = cvtpk_bf16(hi[0], hi[1]); u.u[3] = cvtpk_bf16(hi[2], hi[3]);
        af[mf] = u.s;
      }
      #pragma unroll
      for (int nf = 0; nf < 4; ++nf) {
        const int row = wc * 64 + nf * 16 + lr;
        const int sw = (row & 3) ^ ((row >> 2) & 3);
        bf[nf] = *(const short8*)((const char*)Wl[cur] + row * 64 + ((g ^ sw) << 4));
      }
      #pragma unroll
      for (int mf = 0; mf < 4; ++mf)
        #pragma unroll
        for (int nf = 0; nf < 4; ++nf)
          acc[mf][nf] = __builtin_amdgcn_mfma_f32_16x16x32_bf16(
              af[mf], bf[nf], acc[mf][nf], 0, 0, 0);

      asm volatile("s_waitcnt lgkmcnt(0)" ::: "memory");
      __builtin_amdgcn_s_barrier();
      if (it + 2 < 16) STAGE((it + 2) * 32, cur);
    }
  } else {
    const ushort* A = Abf;
    const ushort* W = Wbase;
    __shared__ __align__(16) ushort Al[2][128 * 64];
    __shared__ __align__(16) ushort Bl[2][128 * 64];
    auto STAGE = [&](int k0, int bufi) {
      #pragma unroll
      for (int u = 0; u < 4; ++u) {
        const int a = t * 16 + u * 4096;
        const int row = a >> 7, ch = (a >> 4) & 7;
        const int kk = k0 + ((ch ^ (row & 7)) << 3);
        gload_lds16(A + (m0 + row) * D_ + kk, (char*)Al[bufi] + a);
        gload_lds16(W + (n0 + row) * D_ + kk, (char*)Bl[bufi] + a);
      }
    };
    STAGE(0, 0);
    STAGE(64, 1);
    #pragma unroll
    for (int it = 0; it < 8; ++it) {
      const int cur = it & 1;
      if (it < 7) asm volatile("s_waitcnt vmcnt(8)" ::: "memory");
      else        asm volatile("s_waitcnt vmcnt(0)" ::: "memory");
      __builtin_amdgcn_s_barrier();
      short8 af[4][2], bf[4][2];
      #pragma unroll
      for (int mf = 0; mf < 4; ++mf)
        #pragma unroll
        for (int ks = 0; ks < 2; ++ks) {
          int row = wr * 64 + mf * 16 + lr;
          af[mf][ks] = *(const short8*)((const char*)Al[cur] + row * 128 + (((ks * 4 + g) ^ (row & 7)) << 4));
          row = wc * 64 + mf * 16 + lr;
          bf[mf][ks] = *(const short8*)((const char*)Bl[cur] + row * 128 + (((ks * 4 + g) ^ (row & 7)) << 4));
        }
      #pragma unroll
      for (int mf = 0; mf < 4; ++mf)
        #pragma unroll
        for (int nf = 0; nf < 4; ++nf)
          #pragma unroll
          for (int ks = 0; ks < 2; ++ks)
            acc[mf][nf] = __builtin_amdgcn_mfma_f32_16x16x32_bf16(
                af[mf][ks], bf[nf][ks], acc[mf][nf], 0, 0, 0);
      asm volatile("s_waitcnt lgkmcnt(0)" ::: "memory");
      __builtin_amdgcn_s_barrier();
      if (it < 6) STAGE((it + 2) * 64, cur);
    }
  }

  if constexpr (MODE == 1) {
    float* C = (float*)C0;
    #pragma unroll
    for (int mf = 0; mf < 4; ++mf)
      #pragma unroll
      for (int nf = 0; nf < 4; ++nf)
        #pragma unroll
        for (int r = 0; r < 4; ++r)
          C[(m0 + wr * 64 + mf * 16 + g * 4 + r) * D_ + n0 + wc * 64 + nf * 16 + lr] =
              acc[mf][nf][r];
  } else {
    if (z < 2) {
      ushort* C = (ushort*)C0 + z * SB;
      #pragma unroll
      for (int mf = 0; mf < 4; ++mf)
        #pragma unroll
        for (int nf = 0; nf < 4; ++nf)
          #pragma unroll
          for (int r = 0; r < 4; ++r)
            C[(m0 + wr * 64 + mf * 16 + g * 4 + r) * D_ + n0 + wc * 64 + nf * 16 + lr] =
                bf16rne(acc[mf][nf][r]);
    } else {
      // V: write transposed per head -> Vt[(b*8+h)*64 + c][kv]
      const int hh = (int)(n0 >> 6) + wc;
      #pragma unroll
      for (int mf = 0; mf < 4; ++mf) {
        const long m = m0 + wr * 64 + mf * 16 + g * 4;
        const int bb = (int)(m >> 10);
        const int kv = (int)(m & 1023);
        #pragma unroll
        for (int nf = 0; nf < 4; ++nf) {
          const int c = nf * 16 + lr;
          uint2 o2;
          o2.x = cvtpk_bf16(acc[mf][nf][0], acc[mf][nf][1]);
          o2.y = cvtpk_bf16(acc[mf][nf][2], acc[mf][nf][3]);
          *(uint2*)&Vt[((long)(bb * 8 + hh) * 64 + c) * (long)N_ + kv] = o2;
        }
      }
    }
  }
}

// ---- attention: 4 waves x 32 q-rows, KV tile 64, 2-phase dbuf staging,
// swapped QK^T, 2^s, in-reg P via permlane swaps, lsum via MFMA-ones. --------
__global__ __launch_bounds__(256) void attn_mfma(
    const ushort* __restrict__ Q, const ushort* __restrict__ K,
    const ushort* __restrict__ Vt, ushort* __restrict__ Hd)
{
  __shared__ __align__(16) ushort Kl[2][64 * 64];
  __shared__ __align__(16) ushort Vl[2][64 * 64];
  const int t = threadIdx.x, lane = t & 63, w = t >> 6;
  const int g = lane >> 4, lr = lane & 15;
  const int bid = blockIdx.x;
  const int z = bid & 127, b = z >> 3, h = z & 7;   // same z -> same XCD
  const int qbase = (bid >> 7) * 128 + w * 32;

  short8 qf[2][2];
  #pragma unroll
  for (int nf = 0; nf < 2; ++nf)
    #pragma unroll
    for (int ks = 0; ks < 2; ++ks)
      qf[nf][ks] = *(const short8*)(Q + (long)(b * N_ + qbase + nf * 16 + lr) * D_ + h * 64 + ks * 32 + g * 8);

  const short8 ones = {0x3F80, 0x3F80, 0x3F80, 0x3F80, 0x3F80, 0x3F80, 0x3F80, 0x3F80};

  f32x4 o[2][4] = {};
  f32x4 acc_l[2] = {};

  const ushort* Kz = K + (long)b * N_ * D_ + h * 64;
  const ushort* Vz = Vt + (long)z * 64 * N_;

  auto STAGE = [&](int kt, int bufi) {
    #pragma unroll
    for (int u = 0; u < 2; ++u) {
      const int a = t * 16 + u * 4096;
      const int row = a >> 7, ch = (a >> 4) & 7;
      const int cc = (ch ^ (row & 7)) << 3;
      gload_lds16(Kz + (long)(kt * 64 + row) * D_ + cc, (char*)Kl[bufi] + a);
      gload_lds16(Vz + (long)row * N_ + kt * 64 + cc, (char*)Vl[bufi] + a);
    }
  };

  STAGE(0, 0);
  __syncthreads();

  for (int kt = 0; kt < 16; ++kt) {
    const int cur = kt & 1;
    if (kt < 15) STAGE(kt + 1, cur ^ 1);

    // S^T[kv][q] = K_tile @ Q^T  (lane: q=lr, kv=16mf+4g+r)
    f32x4 s[4][2] = {};
    __builtin_amdgcn_s_setprio(1);
    #pragma unroll
    for (int mf = 0; mf < 4; ++mf) {
      short8 kf[2];
      #pragma unroll
      for (int ks = 0; ks < 2; ++ks) {
        const int row = mf * 16 + lr;
        kf[ks] = *(const short8*)((const char*)Kl[cur] + row * 128 + (((ks * 4 + g) ^ (row & 7)) << 4));
      }
      #pragma unroll
      for (int nf = 0; nf < 2; ++nf)
        #pragma unroll
        for (int ks = 0; ks < 2; ++ks)
          s[mf][nf] = __builtin_amdgcn_mfma_f32_16x16x32_bf16(kf[ks], qf[nf][ks], s[mf][nf], 0, 0, 0);
    }
    __builtin_amdgcn_s_setprio(0);

    // P = 2^S, pack to bf16, redistribute to PV A-frag layout in-register
    short8 pa[2][2];
    #pragma unroll
    for (int nf = 0; nf < 2; ++nf) {
      uint Apk[4], Bpk[4];
      #pragma unroll
      for (int mf = 0; mf < 4; ++mf) {
        const float e0 = exp2_hw(s[mf][nf][0]);
        const float e1 = exp2_hw(s[mf][nf][1]);
        const float e2 = exp2_hw(s[mf][nf][2]);
        const float e3 = exp2_hw(s[mf][nf][3]);
        Apk[mf] = cvtpk_bf16(e0, e1);
        Bpk[mf] = cvtpk_bf16(e2, e3);
      }
      asm("v_permlane32_swap_b32 %0, %1" : "+v"(Apk[0]), "+v"(Apk[1]));
      asm("v_permlane16_swap_b32 %0, %1" : "+v"(Apk[0]), "+v"(Apk[1]));
      asm("v_permlane32_swap_b32 %0, %1" : "+v"(Bpk[0]), "+v"(Bpk[1]));
      asm("v_permlane16_swap_b32 %0, %1" : "+v"(Bpk[0]), "+v"(Bpk[1]));
      asm("v_permlane32_swap_b32 %0, %1" : "+v"(Apk[2]), "+v"(Apk[3]));
      asm("v_permlane16_swap_b32 %0, %1" : "+v"(Apk[2]), "+v"(Apk[3]));
      asm("v_permlane32_swap_b32 %0, %1" : "+v"(Bpk[2]), "+v"(Bpk[3]));
      asm("v_permlane16_swap_b32 %0, %1" : "+v"(Bpk[2]), "+v"(Bpk[3]));
      U4S8 u0, u1;
      u0.u[0] = Apk[0]; u0.u[1] = Bpk[0]; u0.u[2] = Apk[1]; u0.u[3] = Bpk[1];
      u1.u[0] = Apk[2]; u1.u[1] = Bpk[2]; u1.u[2] = Apk[3]; u1.u[3] = Bpk[3];
      pa[nf][0] = u0.s;
      pa[nf][1] = u1.s;
    }

    // out += P @ V ; row-sums via ones-B MFMA (lands in epilogue layout)
    __builtin_amdgcn_s_setprio(1);
    #pragma unroll
    for (int ks = 0; ks < 2; ++ks) {
      short8 vb[4];
      #pragma unroll
      for (int nf = 0; nf < 4; ++nf) {
        const int row = nf * 16 + lr;
        vb[nf] = *(const short8*)((const char*)Vl[cur] + row * 128 + (((ks * 4 + g) ^ (row & 7)) << 4));
      }
      #pragma unroll
      for (int mf = 0; mf < 2; ++mf) {
        #pragma unroll
        for (int nf = 0; nf < 4; ++nf)
          o[mf][nf] = __builtin_amdgcn_mfma_f32_16x16x32_bf16(pa[mf][ks], vb[nf], o[mf][nf], 0, 0, 0);
        acc_l[mf] = __builtin_amdgcn_mfma_f32_16x16x32_bf16(pa[mf][ks], ones, acc_l[mf], 0, 0, 0);
      }
    }
    __builtin_amdgcn_s_setprio(0);
    __syncthreads();
  }

  // acc_l[mf][r] = row-sum for q = mf*16 + g*4 + r (same for every lr col)
  #pragma unroll
  for (int mf = 0; mf < 2; ++mf)
    #pragma unroll
    for (int r = 0; r < 4; ++r) {
      const float inv = 1.f / acc_l[mf][r];
      const long grow = (long)b * N_ + qbase + mf * 16 + g * 4 + r;
      #pragma unroll
      for (int nf = 0; nf < 4; ++nf)
        Hd[grow * D_ + h * 64 + nf * 16 + lr] = bf16rne(o[mf][nf][r] * inv);
    }
}

extern "C" void kernel_launch(void* const* d_in, const int* in_sizes, int n_in,
                              void* d_out, int out_size, void* d_ws, size_t ws_size,
                              hipStream_t stream) {
  const float* x   = (const float*)d_in[0];
  const float* r   = (const float*)d_in[1];
  const float* x_q = (const float*)d_in[2];
  const float* Wq  = (const float*)d_in[3];
  const float* Wk  = (const float*)d_in[4];
  const float* Wv  = (const float*)d_in[5];
  const float* Wo  = (const float*)d_in[6];

  const long SBe = (long)M_ * D_;      // 8,388,608
  const long WBe = (long)D_ * D_;      // 262,144
  ushort* Qb  = (ushort*)d_ws;
  ushort* Kb  = Qb  + SBe;
  ushort* Vtb = Kb  + SBe;
  ushort* Hdb = Vtb + SBe;
  ushort* Wqb = Hdb + SBe;             // weights contiguous: Wq,Wk,Wv,Wo

  dim3 blk(256);
  castW_k<<<dim3(128, 4), blk, 0, stream>>>(Wq, Wk, Wv, Wo, Wqb, WBe);

  gemm_k<0><<<dim3(1536), blk, 0, stream>>>(x_q, x, r, nullptr, Wqb, Qb, Vtb);

  attn_mfma<<<dim3(1024), blk, 0, stream>>>(Qb, Kb, Vtb, Hdb);

  gemm_k<1><<<dim3(512), blk, 0, stream>>>(nullptr, nullptr, nullptr, Hdb,
                                           Wqb + 3 * WBe, d_out, nullptr);
}